// Round 17
// baseline (149.465 us; speedup 1.0000x reference)
//
#include <hip/hip_runtime.h>
#include <hip/hip_bf16.h>
#include <cstdint>

#define NROWS 262144
#define DIM 128

typedef float f32x4 __attribute__((ext_vector_type(4)));
typedef short s16x8 __attribute__((ext_vector_type(8)));
typedef unsigned short u16x8 __attribute__((ext_vector_type(8)));
typedef unsigned int u32x4 __attribute__((ext_vector_type(4)));

__device__ __forceinline__ unsigned short cvbf(float f){
  unsigned u = __float_as_uint(f);
  return (unsigned short)((u + 0x8000u) >> 16);
}

// ---------------- prep kernel: weight repack (LINEAR, no swizzle) + dtype detect ----------------
// ws[0..65536): W1T bf16, row n=g*64+h (256 x 256B), byte = n*256 + k*2
// ws[65536..73728): W2T bf16, row t=g*16+p (64 x 128B); element slot e (=ks*32+q*8+j)
//   holds W2[g][h(e)][p], h(e) = (e&32)|((e&4)<<2)|((e>>1)&12)|(e&3)  (k-slot permutation
//   matching GEMM1's C^T fragment layout -> GEMM2 needs no hidden transpose), p>=4 zeros.
// ws[73728]: gshift (0=int32 gids, 1=int64) ; ws[73732]: mshift (0=byte mask, 2=int32 mask)
__global__ void prep_kernel(const float* __restrict__ W1, const float* __restrict__ W2,
                            const void* __restrict__ gids_raw, const void* __restrict__ mask_raw,
                            unsigned char* __restrict__ ws){
  int tid = threadIdx.x, bid = blockIdx.x;
  if (bid < 16){
    int chunk = bid*256 + tid;
    int n    = chunk >> 4;
    int kb16 = chunk & 15;
    int d0   = kb16 * 8;
    int g = n >> 6, h = n & 63;
    u16x8 v;
#pragma unroll
    for (int j=0;j<8;++j) v[j] = cvbf(W1[((g*DIM) + d0 + j)*64 + h]);
    unsigned off = (unsigned)n*256 + (unsigned)kb16*16;
    *(u16x8*)(ws + off) = v;
  } else {
#pragma unroll
    for (int i=0;i<16;++i){
      int el = tid + i*256;          // 0..4095 elements of W2T
      int t  = el >> 6;              // row t = g*16+p
      int e  = el & 63;              // k-slot within row
      int g = t >> 4, p = t & 15;
      int h = (e & 32) | ((e & 4) << 2) | ((e >> 1) & 12) | (e & 3);
      float f = (p < 4) ? W2[(g*64 + h)*4 + p] : 0.0f;
      unsigned off = 65536u + (unsigned)t*128 + (unsigned)(e*2);
      *(unsigned short*)(ws + off) = cvbf(f);
    }
    if (tid < 64){
      const int* g32 = (const int*)gids_raw;
      int accg = 0;
#pragma unroll
      for (int i=0;i<8;++i) accg |= g32[(tid*8 + i)*2 + 1];
      const unsigned char* m8 = (const unsigned char*)mask_raw;
      int accm = 0;
#pragma unroll
      for (int i=0;i<16;++i){
        int off = tid*16 + i;
        if (off & 3) accm |= m8[off];
      }
      unsigned long long bg = __ballot(accg != 0);
      unsigned long long bm = __ballot(accm != 0);
      if (tid == 0){
        *(int*)(ws + 73728) = (bg == 0ull) ? 1 : 0;
        *(int*)(ws + 73732) = (bm == 0ull) ? 2 : 0;
      }
    }
  }
}

// ---------------- main kernel: NO LDS, weights read from L2-resident ws; 16 waves/CU ----------------
__global__ __launch_bounds__(256, 2)
void actor_kernel(const float* __restrict__ X, const int* __restrict__ gids,
                  const unsigned char* __restrict__ fmask,
                  const float* __restrict__ b1, const float* __restrict__ b2,
                  const unsigned char* __restrict__ ws, float* __restrict__ out){
  const int tid  = threadIdx.x;
  const int wave = tid >> 6, lane = tid & 63;
  const int q    = lane >> 4, rS = lane & 15;

  const int gshift = *(const int*)(ws + 73728);
  const int mshift = *(const int*)(ws + 73732);

  const long base = (long)blockIdx.x * 256 + wave * 64;
  const f32x4 z = (f32x4){0.f,0.f,0.f,0.f};

#pragma unroll 1
  for (int u=0; u<2; ++u){
    const long row0 = base + u*32 + rS;   // nt=0 row; nt=1 is +16

    // --- loads for both 16-row halves ---
    int gb0, gb1;
    u32x4 mb0, mb1;
    f32x4 xb[2][4][2];
    {
      gb0 = gids[(size_t)row0 << gshift];
      gb1 = gids[(size_t)(row0 + 16) << gshift];
      if (mshift){
        mb0 = *(const u32x4*)(fmask + row0*16);
        mb1 = *(const u32x4*)(fmask + (row0+16)*16);
      } else {
        unsigned w0 = *(const unsigned*)(fmask + row0*4);
        unsigned w1 = *(const unsigned*)(fmask + (row0+16)*4);
        mb0[0]=w0&0xffu; mb0[1]=(w0>>8)&0xffu; mb0[2]=(w0>>16)&0xffu; mb0[3]=w0>>24;
        mb1[0]=w1&0xffu; mb1[1]=(w1>>8)&0xffu; mb1[2]=(w1>>16)&0xffu; mb1[3]=w1>>24;
      }
      const float* xp0 = X + row0 * DIM + q*8;
      const float* xp1 = X + (row0 + 16) * DIM + q*8;
#pragma unroll
      for (int k=0;k<4;++k){
        xb[0][k][0] = *(const f32x4*)(xp0 + k*32);
        xb[0][k][1] = *(const f32x4*)(xp0 + k*32 + 4);
        xb[1][k][0] = *(const f32x4*)(xp1 + k*32);
        xb[1][k][1] = *(const f32x4*)(xp1 + k*32 + 4);
      }
    }
    __builtin_amdgcn_sched_barrier(0);

    // --- convert to bf16 B-fragments (xb dies here) ---
    s16x8 bfr[2][4];
#pragma unroll
    for (int nt=0;nt<2;++nt)
#pragma unroll
      for (int k=0;k<4;++k){
        s16x8 v;
#pragma unroll
        for (int j=0;j<4;++j){ v[j] = (short)cvbf(xb[nt][k][0][j]); v[j+4] = (short)cvbf(xb[nt][k][1][j]); }
        bfr[nt][k] = v;
      }
    __builtin_amdgcn_sched_barrier(0);

    // --- fused GEMM1 -> +b1/relu -> GEMM2; A-frags straight from L2-resident ws ---
    f32x4 acc2[4][2];
#pragma unroll
    for (int p=0;p<8;++p){
      f32x4 aA0, aA1, aB0, aB1;
#pragma unroll
      for (int k=0;k<4;++k){
        const s16x8 sA = *(const s16x8*)(ws + ((2*p  )*16 + rS)*256 + k*64 + q*16);
        const s16x8 sB = *(const s16x8*)(ws + ((2*p+1)*16 + rS)*256 + k*64 + q*16);
        aA0 = __builtin_amdgcn_mfma_f32_16x16x32_bf16(sA, bfr[0][k], (k==0)? z : aA0, 0,0,0);
        aA1 = __builtin_amdgcn_mfma_f32_16x16x32_bf16(sA, bfr[1][k], (k==0)? z : aA1, 0,0,0);
        aB0 = __builtin_amdgcn_mfma_f32_16x16x32_bf16(sB, bfr[0][k], (k==0)? z : aB0, 0,0,0);
        aB1 = __builtin_amdgcn_mfma_f32_16x16x32_bf16(sB, bfr[1][k], (k==0)? z : aB1, 0,0,0);
      }
      const f32x4 b1A = *(const f32x4*)(b1 + (2*p  )*16 + q*4);
      const f32x4 b1B = *(const f32x4*)(b1 + (2*p+1)*16 + q*4);
      const s16x8 af = *(const s16x8*)(ws + 65536 + ((p>>1)*16 + rS)*128
                                       + (p&1)*64 + q*16);
      // nt = 0
      {
        f32x4 vA = aA0 + b1A;
        f32x4 vB = aB0 + b1B;
#pragma unroll
        for (int j=0;j<4;++j){
          vA[j] = vA[j] > 0.f ? vA[j] : 0.f;
          vB[j] = vB[j] > 0.f ? vB[j] : 0.f;
        }
        s16x8 hf;
#pragma unroll
        for (int j=0;j<4;++j){ hf[j] = (short)cvbf(vA[j]); hf[j+4] = (short)cvbf(vB[j]); }
        acc2[p>>1][0] = __builtin_amdgcn_mfma_f32_16x16x32_bf16(
            af, hf, (p&1) ? acc2[p>>1][0] : z, 0,0,0);
      }
      // nt = 1
      {
        f32x4 vA = aA1 + b1A;
        f32x4 vB = aB1 + b1B;
#pragma unroll
        for (int j=0;j<4;++j){
          vA[j] = vA[j] > 0.f ? vA[j] : 0.f;
          vB[j] = vB[j] > 0.f ? vB[j] : 0.f;
        }
        s16x8 hf;
#pragma unroll
        for (int j=0;j<4;++j){ hf[j] = (short)cvbf(vA[j]); hf[j+4] = (short)cvbf(vB[j]); }
        acc2[p>>1][1] = __builtin_amdgcn_mfma_f32_16x16x32_bf16(
            af, hf, (p&1) ? acc2[p>>1][1] : z, 0,0,0);
      }
      __builtin_amdgcn_sched_barrier(0);
    }

    // --- epilogues ---
#pragma unroll
    for (int nt=0;nt<2;++nt){
      int g = nt ? gb1 : gb0;
      u32x4 mb = nt ? mb1 : mb0;
      f32x4 lv = acc2[0][nt];
      lv = (g==1) ? acc2[1][nt] : lv;
      lv = (g==2) ? acc2[2][nt] : lv;
      lv = (g==3) ? acc2[3][nt] : lv;
      const f32x4 bs = *(const f32x4*)(b2 + g*4);
      f32x4 li;
#pragma unroll
      for (int p=0;p<4;++p)
        li[p] = mb[p] ? (lv[p] + bs[p]) : -1e9f;
      float m = fmaxf(fmaxf(li[0],li[1]), fmaxf(li[2],li[3]));
      f32x4 e;
#pragma unroll
      for (int p=0;p<4;++p) e[p] = __expf(li[p] - m);
      float inv = 1.0f / (e[0]+e[1]+e[2]+e[3]);
      f32x4 o;
#pragma unroll
      for (int p=0;p<4;++p) o[p] = e[p] * inv;
      if (q == 0)
        *(f32x4*)(out + (row0 + nt*16)*4) = o;
    }
  }
}

extern "C" void kernel_launch(void* const* d_in, const int* in_sizes, int n_in,
                              void* d_out, int out_size, void* d_ws, size_t ws_size,
                              hipStream_t stream){
  const float* X  = (const float*)d_in[0];
  const void*  gi = d_in[1];
  const void*  fm = d_in[2];
  const float* W1 = (const float*)d_in[3];
  const float* b1 = (const float*)d_in[4];
  const float* W2 = (const float*)d_in[5];
  const float* b2 = (const float*)d_in[6];
  unsigned char* ws = (unsigned char*)d_ws;
  float* out = (float*)d_out;

  prep_kernel<<<dim3(17), dim3(256), 0, stream>>>(W1, W2, gi, fm, ws);
  actor_kernel<<<dim3(1024), dim3(256), 0, stream>>>(X, (const int*)gi,
                                                     (const unsigned char*)fm,
                                                     b1, b2, ws, out);
}

// Round 18
// 44.174 us; speedup vs baseline: 3.3836x; 3.3836x over previous
//
#include <hip/hip_runtime.h>
#include <hip/hip_bf16.h>
#include <cstdint>

#define NROWS 262144
#define DIM 128

typedef float f32x4 __attribute__((ext_vector_type(4)));
typedef short s16x8 __attribute__((ext_vector_type(8)));
typedef unsigned short u16x8 __attribute__((ext_vector_type(8)));
typedef unsigned int u32x4 __attribute__((ext_vector_type(4)));

__device__ __forceinline__ unsigned short cvbf(float f){
  unsigned u = __float_as_uint(f);
  return (unsigned short)((u + 0x8000u) >> 16);
}

__device__ __forceinline__ void ldsload16(const void* gp, void* lp){
  __builtin_amdgcn_global_load_lds((const __attribute__((address_space(1))) void*)gp,
                                   (__attribute__((address_space(3))) void*)lp,
                                   16, 0, 0);
}

// ---------------- prep kernel: weight repack (swizzled) + dtype detect into d_ws ----------------
// ws[0..65536): W1T bf16, row n=g*64+h (256 x 256B), byte = n*256 + (k*2 ^ ((n&7)<<4))
// ws[65536..73728): W2T bf16, row t=g*16+p (64 x 128B); k-slot-permuted W2 (see r9 notes)
// ws[73728]: gshift ; ws[73732]: mshift
__global__ void prep_kernel(const float* __restrict__ W1, const float* __restrict__ W2,
                            const void* __restrict__ gids_raw, const void* __restrict__ mask_raw,
                            unsigned char* __restrict__ ws){
  int tid = threadIdx.x, bid = blockIdx.x;
  if (bid < 16){
    int chunk = bid*256 + tid;
    int n    = chunk >> 4;
    int kb16 = chunk & 15;
    int d0   = kb16 * 8;
    int g = n >> 6, h = n & 63;
    u16x8 v;
#pragma unroll
    for (int j=0;j<8;++j) v[j] = cvbf(W1[((g*DIM) + d0 + j)*64 + h]);
    unsigned off = (unsigned)n*256 + (((unsigned)kb16*16) ^ (((unsigned)(n&7))<<4));
    *(u16x8*)(ws + off) = v;
  } else {
#pragma unroll
    for (int i=0;i<16;++i){
      int el = tid + i*256;
      int t  = el >> 6;
      int e  = el & 63;
      int g = t >> 4, p = t & 15;
      int h = (e & 32) | ((e & 4) << 2) | ((e >> 1) & 12) | (e & 3);
      float f = (p < 4) ? W2[(g*64 + h)*4 + p] : 0.0f;
      unsigned off = 65536u + (unsigned)t*128 + (((unsigned)(e*2)) ^ (((unsigned)(t&7))<<4));
      *(unsigned short*)(ws + off) = cvbf(f);
    }
    if (tid < 64){
      const int* g32 = (const int*)gids_raw;
      int accg = 0;
#pragma unroll
      for (int i=0;i<8;++i) accg |= g32[(tid*8 + i)*2 + 1];
      const unsigned char* m8 = (const unsigned char*)mask_raw;
      int accm = 0;
#pragma unroll
      for (int i=0;i<16;++i){
        int off = tid*16 + i;
        if (off & 3) accm |= m8[off];
      }
      unsigned long long bg = __ballot(accg != 0);
      unsigned long long bm = __ballot(accm != 0);
      if (tid == 0){
        *(int*)(ws + 73728) = (bg == 0ull) ? 1 : 0;
        *(int*)(ws + 73732) = (bm == 0ull) ? 2 : 0;
      }
    }
  }
}

// ---------------- main kernel: group-pair blocks, 38KB LDS, 4 blocks/CU ----------------
#define W2T_OFF   32768
#define B1_OFF    36864
#define PERM_OFF  37376          // short perm[640]
#define HIST_OFF  (PERM_OFF+1280)
#define CUR_OFF   (HIST_OFF+16)
#define NUNITS_OFF (CUR_OFF+16)
#define UG_OFF    (NUNITS_OFF+16) // int local-group per unit [20]
#define UP_OFF    (UG_OFF+80)     // int unit pos [20]
#define LDS_TOTAL (UP_OFF+80)

__global__ __launch_bounds__(256, 2)
void actor_kernel(const float* __restrict__ X, const int* __restrict__ gids,
                  const unsigned char* __restrict__ fmask,
                  const float* __restrict__ b1, const float* __restrict__ b2,
                  const unsigned char* __restrict__ ws, float* __restrict__ out){
  __shared__ char smem[LDS_TOTAL];
  const int tid  = threadIdx.x;
  const int wave = tid >> 6, lane = tid & 63;
  const int q    = lane >> 4, rS = lane & 15;
  const int swzA = (rS & 7) << 4;

  const int pair = blockIdx.x >> 9;                 // 0: groups {0,1}, 1: groups {2,3}
  const long base = (long)(blockIdx.x & 511) * 512; // row window

  const int gshift = *(const int*)(ws + 73728);
  const int mshift = *(const int*)(ws + 73732);

  short* perm = (short*)(smem + PERM_OFF);
  int* hist = (int*)(smem + HIST_OFF);
  int* cur  = (int*)(smem + CUR_OFF);
  int* ug   = (int*)(smem + UG_OFF);
  int* up   = (int*)(smem + UP_OFF);

  // --- stage this pair's weight slices (async) ---
#pragma unroll
  for (int i=0;i<8;++i){
    int off = i*4096 + wave*1024;
    ldsload16(ws + pair*32768 + off + lane*16, smem + off);
  }
  ldsload16(ws + 65536 + pair*4096 + wave*1024 + lane*16,
            smem + W2T_OFF + wave*1024 + lane*16);
  if (wave == 0 && lane < 32)
    ldsload16((const unsigned char*)b1 + pair*512 + lane*16, smem + B1_OFF + lane*16);

  // --- block-local bucketing of this window's rows into the pair's two groups ---
  if (tid < 4) hist[tid] = 0;
#pragma unroll
  for (int i = 0; i < 3; ++i){
    int e = tid + i*256;
    if (e < 640) perm[e] = -1;
  }
  __syncthreads();
  const int g0 = gids[(size_t)(base + tid) << gshift] & 3;
  const int g1 = gids[(size_t)(base + 256 + tid) << gshift] & 3;
  atomicAdd(&hist[g0], 1);
  atomicAdd(&hist[g1], 1);
  __syncthreads();
  if (tid == 0){
    int s = 0, n = 0;
    for (int gg=0; gg<2; ++gg){
      int g = pair*2 + gg;
      cur[g] = s;
      int padded = ((hist[g] + 31) >> 5) << 5;
      for (int k=0; k<padded; k+=32){ ug[n] = gg; up[n] = s + k; ++n; }
      s += padded;
    }
    *(int*)(smem + NUNITS_OFF) = n;
  }
  __syncthreads();
  if ((g0 >> 1) == pair){ int p0 = atomicAdd(&cur[g0], 1); perm[p0] = (short)tid; }
  if ((g1 >> 1) == pair){ int p1 = atomicAdd(&cur[g1], 1); perm[p1] = (short)(256 + tid); }
  __syncthreads();   // also drains weight staging
  const int nunits = *(const int*)(smem + NUNITS_OFF);

  const f32x4 z = (f32x4){0.f,0.f,0.f,0.f};

#pragma unroll 1
  for (int uu = 0; uu < 5; ++uu){
    const int idx = wave + uu*4;
    if (idx >= nunits) break;
    const int gg  = ug[idx];           // local group 0/1
    const int pos = up[idx];
    const int r0l = perm[pos + rS];
    const int r1l = perm[pos + 16 + rS];
    const long rr0 = base + (r0l < 0 ? 0 : r0l);
    const long rr1 = base + (r1l < 0 ? 0 : r1l);

    // --- masks ---
    u32x4 mb0, mb1;
    if (mshift){
      mb0 = *(const u32x4*)(fmask + rr0*16);
      mb1 = *(const u32x4*)(fmask + rr1*16);
    } else {
      unsigned w0 = *(const unsigned*)(fmask + rr0*4);
      unsigned w1 = *(const unsigned*)(fmask + rr1*4);
      mb0[0]=w0&0xffu; mb0[1]=(w0>>8)&0xffu; mb0[2]=(w0>>16)&0xffu; mb0[3]=w0>>24;
      mb1[0]=w1&0xffu; mb1[1]=(w1>>8)&0xffu; mb1[2]=(w1>>16)&0xffu; mb1[3]=w1>>24;
    }

    // --- X loads (gathered within the 512-row window) ---
    f32x4 xb[2][4][2];
    {
      const float* xp0 = X + rr0 * DIM + q*8;
      const float* xp1 = X + rr1 * DIM + q*8;
#pragma unroll
      for (int k=0;k<4;++k){
        xb[0][k][0] = *(const f32x4*)(xp0 + k*32);
        xb[0][k][1] = *(const f32x4*)(xp0 + k*32 + 4);
        xb[1][k][0] = *(const f32x4*)(xp1 + k*32);
        xb[1][k][1] = *(const f32x4*)(xp1 + k*32 + 4);
      }
    }
    __builtin_amdgcn_sched_barrier(0);

    // --- cvt to bf16 B-fragments ---
    s16x8 bfr[2][4];
#pragma unroll
    for (int nt=0;nt<2;++nt)
#pragma unroll
      for (int k=0;k<4;++k){
        s16x8 v;
#pragma unroll
        for (int j=0;j<4;++j){ v[j] = (short)cvbf(xb[nt][k][0][j]); v[j+4] = (short)cvbf(xb[nt][k][1][j]); }
        bfr[nt][k] = v;
      }
    __builtin_amdgcn_sched_barrier(0);

    // --- fused GEMM1(local group gg) -> +b1/relu -> GEMM2, pinned ---
    f32x4 acc2[2];
#pragma unroll
    for (int pp=0;pp<2;++pp){
      const int p = 2*gg + pp;           // local mt-pair index (0..3)
      f32x4 aA0, aA1, aB0, aB1;
#pragma unroll
      for (int k=0;k<4;++k){
        const s16x8 sA = *(const s16x8*)(smem + ((2*p  )*16 + rS)*256 + ((k*64 + q*16) ^ swzA));
        const s16x8 sB = *(const s16x8*)(smem + ((2*p+1)*16 + rS)*256 + ((k*64 + q*16) ^ swzA));
        aA0 = __builtin_amdgcn_mfma_f32_16x16x32_bf16(sA, bfr[0][k], (k==0)? z : aA0, 0,0,0);
        aA1 = __builtin_amdgcn_mfma_f32_16x16x32_bf16(sA, bfr[1][k], (k==0)? z : aA1, 0,0,0);
        aB0 = __builtin_amdgcn_mfma_f32_16x16x32_bf16(sB, bfr[0][k], (k==0)? z : aB0, 0,0,0);
        aB1 = __builtin_amdgcn_mfma_f32_16x16x32_bf16(sB, bfr[1][k], (k==0)? z : aB1, 0,0,0);
      }
      const f32x4 b1A = *(const f32x4*)(smem + B1_OFF + (2*p  )*64 + q*16);
      const f32x4 b1B = *(const f32x4*)(smem + B1_OFF + (2*p+1)*64 + q*16);
      const s16x8 af = *(const s16x8*)(smem + W2T_OFF + (gg*16 + rS)*128
                                       + ((pp*64 + q*16) ^ swzA));
      {
        f32x4 vA = aA0 + b1A, vB = aB0 + b1B;
#pragma unroll
        for (int j=0;j<4;++j){ vA[j] = vA[j] > 0.f ? vA[j] : 0.f; vB[j] = vB[j] > 0.f ? vB[j] : 0.f; }
        s16x8 hf;
#pragma unroll
        for (int j=0;j<4;++j){ hf[j] = (short)cvbf(vA[j]); hf[j+4] = (short)cvbf(vB[j]); }
        acc2[0] = __builtin_amdgcn_mfma_f32_16x16x32_bf16(af, hf, pp ? acc2[0] : z, 0,0,0);
      }
      {
        f32x4 vA = aA1 + b1A, vB = aB1 + b1B;
#pragma unroll
        for (int j=0;j<4;++j){ vA[j] = vA[j] > 0.f ? vA[j] : 0.f; vB[j] = vB[j] > 0.f ? vB[j] : 0.f; }
        s16x8 hf;
#pragma unroll
        for (int j=0;j<4;++j){ hf[j] = (short)cvbf(vA[j]); hf[j+4] = (short)cvbf(vB[j]); }
        acc2[1] = __builtin_amdgcn_mfma_f32_16x16x32_bf16(af, hf, pp ? acc2[1] : z, 0,0,0);
      }
      __builtin_amdgcn_sched_barrier(0);
    }

    // --- epilogues (group uniform) ---
    const f32x4 bs = *(const f32x4*)(b2 + (pair*2 + gg)*4);
#pragma unroll
    for (int nt=0;nt<2;++nt){
      u32x4 mb = nt ? mb1 : mb0;
      f32x4 lv = acc2[nt];
      f32x4 li;
#pragma unroll
      for (int p=0;p<4;++p)
        li[p] = mb[p] ? (lv[p] + bs[p]) : -1e9f;
      float m = fmaxf(fmaxf(li[0],li[1]), fmaxf(li[2],li[3]));
      f32x4 e;
#pragma unroll
      for (int p=0;p<4;++p) e[p] = __expf(li[p] - m);
      float inv = 1.0f / (e[0]+e[1]+e[2]+e[3]);
      f32x4 o;
#pragma unroll
      for (int p=0;p<4;++p) o[p] = e[p] * inv;
      int rl = nt ? r1l : r0l;
      long rr = nt ? rr1 : rr0;
      if (q == 0 && rl >= 0)
        *(f32x4*)(out + rr*4) = o;
    }
  }
}

extern "C" void kernel_launch(void* const* d_in, const int* in_sizes, int n_in,
                              void* d_out, int out_size, void* d_ws, size_t ws_size,
                              hipStream_t stream){
  const float* X  = (const float*)d_in[0];
  const void*  gi = d_in[1];
  const void*  fm = d_in[2];
  const float* W1 = (const float*)d_in[3];
  const float* b1 = (const float*)d_in[4];
  const float* W2 = (const float*)d_in[5];
  const float* b2 = (const float*)d_in[6];
  unsigned char* ws = (unsigned char*)d_ws;
  float* out = (float*)d_out;

  prep_kernel<<<dim3(17), dim3(256), 0, stream>>>(W1, W2, gi, fm, ws);
  actor_kernel<<<dim3(1024), dim3(256), 0, stream>>>(X, (const int*)gi,
                                                     (const unsigned char*)fm,
                                                     b1, b2, ws, out);
}

// Round 19
// 37.819 us; speedup vs baseline: 3.9521x; 1.1680x over previous
//
#include <hip/hip_runtime.h>
#include <hip/hip_bf16.h>
#include <cstdint>

#define NROWS 262144
#define DIM 128

typedef float f32x4 __attribute__((ext_vector_type(4)));
typedef short s16x8 __attribute__((ext_vector_type(8)));
typedef unsigned short u16x8 __attribute__((ext_vector_type(8)));
typedef unsigned int u32x4 __attribute__((ext_vector_type(4)));

__device__ __forceinline__ unsigned short cvbf(float f){
  unsigned u = __float_as_uint(f);
  return (unsigned short)((u + 0x8000u) >> 16);
}

__device__ __forceinline__ void ldsload16(const void* gp, void* lp){
  __builtin_amdgcn_global_load_lds((const __attribute__((address_space(1))) void*)gp,
                                   (__attribute__((address_space(3))) void*)lp,
                                   16, 0, 0);
}

// ---------------- prep kernel: weight repack + dtype detect into d_ws ----------------
// ws[0..65536): W1T bf16, row n=g*64+h (256 x 256B), byte = n*256 + (k*2 ^ ((n&7)<<4))
// ws[65536..73728): W2T bf16, row t=g*16+p (64 x 128B); element slot e (=ks*32+q*8+j)
//   holds W2[g][h(e)][p], h(e) = (e&32)|((e&4)<<2)|((e>>1)&12)|(e&3)  (k-slot permutation
//   matching GEMM1's C^T fragment layout -> GEMM2 needs no hidden transpose), p>=4 zeros.
// ws[73728]: gshift (0=int32 gids, 1=int64) ; ws[73732]: mshift (0=byte mask, 2=int32 mask)
__global__ void prep_kernel(const float* __restrict__ W1, const float* __restrict__ W2,
                            const void* __restrict__ gids_raw, const void* __restrict__ mask_raw,
                            unsigned char* __restrict__ ws){
  int tid = threadIdx.x, bid = blockIdx.x;
  if (bid < 16){
    int chunk = bid*256 + tid;
    int n    = chunk >> 4;
    int kb16 = chunk & 15;
    int d0   = kb16 * 8;
    int g = n >> 6, h = n & 63;
    u16x8 v;
#pragma unroll
    for (int j=0;j<8;++j) v[j] = cvbf(W1[((g*DIM) + d0 + j)*64 + h]);
    unsigned off = (unsigned)n*256 + (((unsigned)kb16*16) ^ (((unsigned)(n&7))<<4));
    *(u16x8*)(ws + off) = v;
  } else {
#pragma unroll
    for (int i=0;i<16;++i){
      int el = tid + i*256;          // 0..4095 elements of W2T
      int t  = el >> 6;              // row t = g*16+p
      int e  = el & 63;              // k-slot within row
      int g = t >> 4, p = t & 15;
      int h = (e & 32) | ((e & 4) << 2) | ((e >> 1) & 12) | (e & 3);
      float f = (p < 4) ? W2[(g*64 + h)*4 + p] : 0.0f;
      unsigned off = 65536u + (unsigned)t*128 + (((unsigned)(e*2)) ^ (((unsigned)(t&7))<<4));
      *(unsigned short*)(ws + off) = cvbf(f);
    }
    if (tid < 64){
      const int* g32 = (const int*)gids_raw;
      int accg = 0;
#pragma unroll
      for (int i=0;i<8;++i) accg |= g32[(tid*8 + i)*2 + 1];
      const unsigned char* m8 = (const unsigned char*)mask_raw;
      int accm = 0;
#pragma unroll
      for (int i=0;i<16;++i){
        int off = tid*16 + i;
        if (off & 3) accm |= m8[off];
      }
      unsigned long long bg = __ballot(accg != 0);
      unsigned long long bm = __ballot(accm != 0);
      if (tid == 0){
        *(int*)(ws + 73728) = (bg == 0ull) ? 1 : 0;
        *(int*)(ws + 73732) = (bm == 0ull) ? 2 : 0;
      }
    }
  }
}

// ---------------- main kernel: round-9 shape + wave phase-skew ----------------
#define LDS_W2T 65536
#define LDS_B1  (65536+8192)
#define LDS_TOTAL (65536+8192+1024)

__global__ __launch_bounds__(256, 2)
void actor_kernel(const float* __restrict__ X, const int* __restrict__ gids,
                  const unsigned char* __restrict__ fmask,
                  const float* __restrict__ b1, const float* __restrict__ b2,
                  const unsigned char* __restrict__ ws, float* __restrict__ out){
  __shared__ char smem[LDS_TOTAL];
  const int tid  = threadIdx.x;
  const int wave = tid >> 6, lane = tid & 63;
  const int q    = lane >> 4, rS = lane & 15;
  const int swzA = (rS & 7) << 4;

  const int gshift = *(const int*)(ws + 73728);
  const int mshift = *(const int*)(ws + 73732);

  // --- stage W1T + W2T + b1 to LDS once per block ---
#pragma unroll
  for (int i=0;i<16;++i){
    int off = i*4096 + wave*1024;
    ldsload16(ws + off + lane*16, smem + off);
  }
#pragma unroll
  for (int i=0;i<2;++i){
    int off = i*4096 + wave*1024;
    ldsload16(ws + 65536 + off + lane*16, smem + LDS_W2T + off);
  }
  if (wave == 0)
    ldsload16((const unsigned char*)b1 + lane*16, smem + LDS_B1);
  __syncthreads();   // weights resident

  // de-lockstep the 4 waves' load/compute phases (~0.8us per wave step):
  // while skewed-out waves sleep, earlier waves' X loads own the memory pipe;
  // afterwards load and compute phases of different waves tile the round.
  for (int i = 0; i < 2*wave; ++i) __builtin_amdgcn_s_sleep(15);

  const long base = (long)blockIdx.x * 512 + wave * 128;
  const f32x4 z = (f32x4){0.f,0.f,0.f,0.f};

#pragma unroll 1
  for (int u=0; u<4; ++u){
    const long row0 = base + u*32 + rS;   // nt=0 row; nt=1 is +16

    // --- loads for both 16-row halves (issued together, TLP hides latency) ---
    int gb0, gb1;
    u32x4 mb0, mb1;
    f32x4 xb[2][4][2];
    {
      gb0 = gids[(size_t)row0 << gshift];
      gb1 = gids[(size_t)(row0 + 16) << gshift];
      if (mshift){
        mb0 = *(const u32x4*)(fmask + row0*16);
        mb1 = *(const u32x4*)(fmask + (row0+16)*16);
      } else {
        unsigned w0 = *(const unsigned*)(fmask + row0*4);
        unsigned w1 = *(const unsigned*)(fmask + (row0+16)*4);
        mb0[0]=w0&0xffu; mb0[1]=(w0>>8)&0xffu; mb0[2]=(w0>>16)&0xffu; mb0[3]=w0>>24;
        mb1[0]=w1&0xffu; mb1[1]=(w1>>8)&0xffu; mb1[2]=(w1>>16)&0xffu; mb1[3]=w1>>24;
      }
      const float* xp0 = X + row0 * DIM + q*8;
      const float* xp1 = X + (row0 + 16) * DIM + q*8;
#pragma unroll
      for (int k=0;k<4;++k){
        xb[0][k][0] = *(const f32x4*)(xp0 + k*32);
        xb[0][k][1] = *(const f32x4*)(xp0 + k*32 + 4);
        xb[1][k][0] = *(const f32x4*)(xp1 + k*32);
        xb[1][k][1] = *(const f32x4*)(xp1 + k*32 + 4);
      }
    }
    __builtin_amdgcn_sched_barrier(0);

    // --- convert to bf16 B-fragments (xb dies here) ---
    s16x8 bfr[2][4];
#pragma unroll
    for (int nt=0;nt<2;++nt)
#pragma unroll
      for (int k=0;k<4;++k){
        s16x8 v;
#pragma unroll
        for (int j=0;j<4;++j){ v[j] = (short)cvbf(xb[nt][k][0][j]); v[j+4] = (short)cvbf(xb[nt][k][1][j]); }
        bfr[nt][k] = v;
      }
    __builtin_amdgcn_sched_barrier(0);

    // --- fused GEMM1 -> +b1/relu -> GEMM2, per mt-pair; each LDS read feeds 2 MFMAs ---
    f32x4 acc2[4][2];
#pragma unroll
    for (int p=0;p<8;++p){
      f32x4 aA0, aA1, aB0, aB1;
#pragma unroll
      for (int k=0;k<4;++k){
        const s16x8 sA = *(const s16x8*)(smem + ((2*p  )*16 + rS)*256 + ((k*64 + q*16) ^ swzA));
        const s16x8 sB = *(const s16x8*)(smem + ((2*p+1)*16 + rS)*256 + ((k*64 + q*16) ^ swzA));
        aA0 = __builtin_amdgcn_mfma_f32_16x16x32_bf16(sA, bfr[0][k], (k==0)? z : aA0, 0,0,0);
        aA1 = __builtin_amdgcn_mfma_f32_16x16x32_bf16(sA, bfr[1][k], (k==0)? z : aA1, 0,0,0);
        aB0 = __builtin_amdgcn_mfma_f32_16x16x32_bf16(sB, bfr[0][k], (k==0)? z : aB0, 0,0,0);
        aB1 = __builtin_amdgcn_mfma_f32_16x16x32_bf16(sB, bfr[1][k], (k==0)? z : aB1, 0,0,0);
      }
      const f32x4 b1A = *(const f32x4*)(smem + LDS_B1 + (2*p  )*64 + q*16);
      const f32x4 b1B = *(const f32x4*)(smem + LDS_B1 + (2*p+1)*64 + q*16);
      const s16x8 af = *(const s16x8*)(smem + LDS_W2T + ((p>>1)*16 + rS)*128
                                       + (((p&1)*64 + q*16) ^ swzA));
      // nt = 0
      {
        f32x4 vA = aA0 + b1A;
        f32x4 vB = aB0 + b1B;
#pragma unroll
        for (int j=0;j<4;++j){
          vA[j] = vA[j] > 0.f ? vA[j] : 0.f;
          vB[j] = vB[j] > 0.f ? vB[j] : 0.f;
        }
        s16x8 hf;
#pragma unroll
        for (int j=0;j<4;++j){ hf[j] = (short)cvbf(vA[j]); hf[j+4] = (short)cvbf(vB[j]); }
        acc2[p>>1][0] = __builtin_amdgcn_mfma_f32_16x16x32_bf16(
            af, hf, (p&1) ? acc2[p>>1][0] : z, 0,0,0);
      }
      // nt = 1
      {
        f32x4 vA = aA1 + b1A;
        f32x4 vB = aB1 + b1B;
#pragma unroll
        for (int j=0;j<4;++j){
          vA[j] = vA[j] > 0.f ? vA[j] : 0.f;
          vB[j] = vB[j] > 0.f ? vB[j] : 0.f;
        }
        s16x8 hf;
#pragma unroll
        for (int j=0;j<4;++j){ hf[j] = (short)cvbf(vA[j]); hf[j+4] = (short)cvbf(vB[j]); }
        acc2[p>>1][1] = __builtin_amdgcn_mfma_f32_16x16x32_bf16(
            af, hf, (p&1) ? acc2[p>>1][1] : z, 0,0,0);
      }
      __builtin_amdgcn_sched_barrier(0);
    }

    // --- epilogue nt=0 ---
    {
      int g = gb0;
      f32x4 lv = acc2[0][0];
      lv = (g==1) ? acc2[1][0] : lv;
      lv = (g==2) ? acc2[2][0] : lv;
      lv = (g==3) ? acc2[3][0] : lv;
      const f32x4 bs = *(const f32x4*)(b2 + g*4);
      f32x4 li;
#pragma unroll
      for (int p=0;p<4;++p)
        li[p] = mb0[p] ? (lv[p] + bs[p]) : -1e9f;
      float m = fmaxf(fmaxf(li[0],li[1]), fmaxf(li[2],li[3]));
      f32x4 e;
#pragma unroll
      for (int p=0;p<4;++p) e[p] = __expf(li[p] - m);
      float inv = 1.0f / (e[0]+e[1]+e[2]+e[3]);
      f32x4 o;
#pragma unroll
      for (int p=0;p<4;++p) o[p] = e[p] * inv;
      if (q == 0)
        *(f32x4*)(out + row0*4) = o;
    }
    // --- epilogue nt=1 ---
    {
      int g = gb1;
      f32x4 lv = acc2[0][1];
      lv = (g==1) ? acc2[1][1] : lv;
      lv = (g==2) ? acc2[2][1] : lv;
      lv = (g==3) ? acc2[3][1] : lv;
      const f32x4 bs = *(const f32x4*)(b2 + g*4);
      f32x4 li;
#pragma unroll
      for (int p=0;p<4;++p)
        li[p] = mb1[p] ? (lv[p] + bs[p]) : -1e9f;
      float m = fmaxf(fmaxf(li[0],li[1]), fmaxf(li[2],li[3]));
      f32x4 e;
#pragma unroll
      for (int p=0;p<4;++p) e[p] = __expf(li[p] - m);
      float inv = 1.0f / (e[0]+e[1]+e[2]+e[3]);
      f32x4 o;
#pragma unroll
      for (int p=0;p<4;++p) o[p] = e[p] * inv;
      if (q == 0)
        *(f32x4*)(out + (row0+16)*4) = o;
    }
  }
}

extern "C" void kernel_launch(void* const* d_in, const int* in_sizes, int n_in,
                              void* d_out, int out_size, void* d_ws, size_t ws_size,
                              hipStream_t stream){
  const float* X  = (const float*)d_in[0];
  const void*  gi = d_in[1];
  const void*  fm = d_in[2];
  const float* W1 = (const float*)d_in[3];
  const float* b1 = (const float*)d_in[4];
  const float* W2 = (const float*)d_in[5];
  const float* b2 = (const float*)d_in[6];
  unsigned char* ws = (unsigned char*)d_ws;
  float* out = (float*)d_out;

  prep_kernel<<<dim3(17), dim3(256), 0, stream>>>(W1, W2, gi, fm, ws);
  actor_kernel<<<dim3(512), dim3(256), 0, stream>>>(X, (const int*)gi,
                                                    (const unsigned char*)fm,
                                                    b1, b2, ws, out);
}